// Round 3
// baseline (257.717 us; speedup 1.0000x reference)
//
#include <hip/hip_runtime.h>

#define NODES 128
#define NFEAT 256
#define BATCH 512
#define KTOT  (NODES * NFEAT)   // 32768, stage-3 K

typedef __bf16 bf16_t;
typedef bf16_t bf16x4 __attribute__((ext_vector_type(4)));
typedef bf16_t bf16x8 __attribute__((ext_vector_type(8)));
typedef float  f32x4  __attribute__((ext_vector_type(4)));

#define BK    32
#define LDK   40     // fused12 As row stride (80B)
#define LDK3  36     // k_out LDS row stride (72B, conflict-spread)
#define BK2   64
#define LDK2  72     // fp32-fallback k_out row stride
#define TILE  128

// Workgroup barrier WITHOUT the vmcnt(0) drain __syncthreads() emits.
// Only LDS (lgkmcnt) visibility is needed; global prefetch loads stay in flight.
__device__ __forceinline__ void bar() {
    asm volatile("s_waitcnt lgkmcnt(0)\n\ts_barrier" ::: "memory");
}

__device__ __forceinline__ bf16x8 cvt8(const float4 a, const float4 b) {
    bf16x8 t;
    t[0] = (bf16_t)a.x; t[1] = (bf16_t)a.y; t[2] = (bf16_t)a.z; t[3] = (bf16_t)a.w;
    t[4] = (bf16_t)b.x; t[5] = (bf16_t)b.y; t[6] = (bf16_t)b.z; t[7] = (bf16_t)b.w;
    return t;
}

// ---- fp32 128x32 tile: reg-load / LDS-store (fused12 stage 1) ----
struct XT { float4 v[4]; };
__device__ __forceinline__ void xload(const float* __restrict__ src, int ld, int k0,
                                      int tid, XT& t) {
#pragma unroll
    for (int i = 0; i < 2; i++) {
        int f = tid + i * 256, r = f >> 2, c = f & 3;
        t.v[2 * i]     = *(const float4*)(src + (size_t)r * ld + k0 + c * 8);
        t.v[2 * i + 1] = *(const float4*)(src + (size_t)r * ld + k0 + c * 8 + 4);
    }
}
__device__ __forceinline__ void xstore(bf16_t* __restrict__ dst, int tid, const XT& t) {
#pragma unroll
    for (int i = 0; i < 2; i++) {
        int f = tid + i * 256, r = f >> 2, c = f & 3;
        *(bf16x8*)(dst + r * LDK + c * 8) = cvt8(t.v[2 * i], t.v[2 * i + 1]);
    }
}

// ---- fp32 128x64 tile (fp32-fallback k_out B) ----
struct XT2 { float4 v[8]; };
__device__ __forceinline__ void xload2(const float* __restrict__ src, int ld, int k0,
                                       int tid, XT2& t) {
#pragma unroll
    for (int i = 0; i < 4; i++) {
        int f = tid + i * 256, r = f >> 3, c = f & 7;
        t.v[2 * i]     = *(const float4*)(src + (size_t)r * ld + k0 + c * 8);
        t.v[2 * i + 1] = *(const float4*)(src + (size_t)r * ld + k0 + c * 8 + 4);
    }
}
__device__ __forceinline__ void xstore2(bf16_t* __restrict__ dst, int tid, const XT2& t) {
#pragma unroll
    for (int i = 0; i < 4; i++) {
        int f = tid + i * 256, r = f >> 3, c = f & 7;
        *(bf16x8*)(dst + r * LDK2 + c * 8) = cvt8(t.v[2 * i], t.v[2 * i + 1]);
    }
}
struct AT2 { bf16x8 v[4]; };
__device__ __forceinline__ void aload2(const bf16_t* __restrict__ src, int ld, int k0,
                                       int tid, AT2& t) {
#pragma unroll
    for (int i = 0; i < 4; i++) {
        int f = tid + i * 256, r = f >> 3, c = f & 7;
        t.v[i] = *(const bf16x8*)(src + (size_t)r * ld + k0 + c * 8);
    }
}
__device__ __forceinline__ void astore2(bf16_t* __restrict__ dst, int tid, const AT2& t) {
#pragma unroll
    for (int i = 0; i < 4; i++) {
        int f = tid + i * 256, r = f >> 3, c = f & 7;
        *(bf16x8*)(dst + r * LDK2 + c * 8) = t.v[i];
    }
}

// ---- prep: fc_w fp32->bf16 (blocks 0..nconv-1) + gcn_w transpose (last 64) ----
__global__ __launch_bounds__(256)
void k_prep(const float* __restrict__ w, bf16_t* __restrict__ wT,
            const float* __restrict__ fcw, bf16_t* __restrict__ fcwb, int nconv) {
    const int bid = blockIdx.x;
    if (bid < nconv) {
        const size_t base = ((size_t)bid * 256 + threadIdx.x) * 16;
        const float4 a0 = *(const float4*)(fcw + base);
        const float4 a1 = *(const float4*)(fcw + base + 4);
        const float4 a2 = *(const float4*)(fcw + base + 8);
        const float4 a3 = *(const float4*)(fcw + base + 12);
        *(bf16x8*)(fcwb + base)     = cvt8(a0, a1);
        *(bf16x8*)(fcwb + base + 8) = cvt8(a2, a3);
        return;
    }
    const int g0 = (bid - nconv) * 4;
    const int k  = threadIdx.x;
    const float4 v = *(const float4*)(w + (size_t)k * NFEAT + g0);
    wT[(size_t)(g0 + 0) * NFEAT + k] = (bf16_t)v.x;
    wT[(size_t)(g0 + 1) * NFEAT + k] = (bf16_t)v.y;
    wT[(size_t)(g0 + 2) * NFEAT + k] = (bf16_t)v.z;
    wT[(size_t)(g0 + 3) * NFEAT + k] = (bf16_t)v.w;
}

// ---- fused stages 1+2 ----
// Round-0's proven dbuf pipeline for stage 1, but As[2] ALIASED onto the Sb
// region (As dead once Sb is written) -> LDS = 32 KB -> 4 blk/CU, and grid
// 1024 = exactly one full round at 16 waves/CU (round 0 ran 3-then-1).
// Stage 2 reads adj reg-direct (contiguous fp32 = A-frag layout) with a
// static ping-pong one-step prefetch.
__global__ __launch_bounds__(256, 4)
void k_fused12(const float* __restrict__ x, const float* __restrict__ adj,
               const bf16_t* __restrict__ wT, const float* __restrict__ gcn_b,
               bf16_t* __restrict__ mid) {
    __shared__ __align__(16) bf16_t smem[TILE * 128];   // 32 KB union: Sb | As[2]
    bf16_t* Sb = smem;
#define AS(bf) (smem + (bf) * (TILE * LDK))             // 2 x 10 KB inside Sb

    // XCD swizzle: both g-tiles of one batch adjacent on the SAME XCD.
    const int id  = blockIdx.x;
    const int xcd = id & 7, jj = id >> 3;
    const int b   = (xcd << 6) | (jj >> 1);             // bijective for 1024 ids
    const int n0  = (jj & 1) * TILE;
    const int tid = threadIdx.x;
    const int lane = tid & 63, w = tid >> 6, wm = w & 1, wn = w >> 1;
    const int l15 = lane & 15, q = lane >> 4;
    const float* xb   = x   + (size_t)b * NODES * NFEAT;
    const float* adjb = adj + (size_t)b * NODES * NODES;

    const bf16_t* wrow[4];
#pragma unroll
    for (int j = 0; j < 4; j++)
        wrow[j] = wT + (size_t)(n0 + wn * 64 + j * 16 + l15) * NFEAT + q * 8;

    // ---- stage 1: S = x[b] @ W  (K=256, 8 k-steps, dist-3 dbuf pipeline) ----
    f32x4 acc[4][4] = {};
    {
        XT r[3];
        xload(xb, NFEAT, 0 * BK, tid, r[0]);
        xload(xb, NFEAT, 1 * BK, tid, r[1]);
        xload(xb, NFEAT, 2 * BK, tid, r[2]);
        xstore(AS(0), tid, r[0]);
        bar();
#pragma unroll
        for (int k = 0; k < 8; k++) {
            if (k + 3 < 8) xload(xb, NFEAT, (k + 3) * BK, tid, r[k % 3]);
            bf16x8 bcur[4];
#pragma unroll
            for (int j = 0; j < 4; j++) bcur[j] = *(const bf16x8*)(wrow[j] + k * BK);
            bf16x8 a[4];
#pragma unroll
            for (int i = 0; i < 4; i++)
                a[i] = *(const bf16x8*)(AS(k & 1) + (wm * 64 + i * 16 + l15) * LDK + q * 8);
#pragma unroll
            for (int i = 0; i < 4; i++)
#pragma unroll
                for (int j = 0; j < 4; j++)
                    acc[i][j] = __builtin_amdgcn_mfma_f32_16x16x32_bf16(a[i], bcur[j], acc[i][j], 0, 0, 0);
            if (k + 1 < 8) xstore(AS((k + 1) & 1), tid, r[(k + 1) % 3]);
            bar();   // k=7's bar: all As reads done -> Sb region free
        }
    }

    // issue stage-2 k=0 adj loads early (overlap with Sb writes + barrier)
    const float* aa = adjb + (size_t)(wm * 64 + l15) * NODES + q * 8;
    float4 p0[4][2];
#pragma unroll
    for (int i = 0; i < 4; i++) {
        p0[i][0] = *(const float4*)(aa + (size_t)i * 16 * NODES);
        p0[i][1] = *(const float4*)(aa + (size_t)i * 16 * NODES + 4);
    }

    // S -> Sb[g][m], XOR chunk swizzle: slot = (m>>3) ^ (g&15)
#pragma unroll
    for (int i = 0; i < 4; i++)
#pragma unroll
        for (int j = 0; j < 4; j++) {
            int m = wm * 64 + i * 16 + q * 4;
            int g = wn * 64 + j * 16 + l15;
            int slot = (m >> 3) ^ (g & 15);
            bf16x4 v;
            v[0] = (bf16_t)acc[i][j][0]; v[1] = (bf16_t)acc[i][j][1];
            v[2] = (bf16_t)acc[i][j][2]; v[3] = (bf16_t)acc[i][j][3];
            *(bf16x4*)(&Sb[g * 128 + slot * 8 + (m & 7)]) = v;
        }
    bf16x8 pb[2][4];
#pragma unroll
    for (int i = 0; i < 4; i++) pb[0][i] = cvt8(p0[i][0], p0[i][1]);
    bar();

    // ---- stage 2: mid = adj[b] @ S  (K=128, 4 k-steps, ping-pong prefetch) ----
    f32x4 acc2[4][4] = {};
#pragma unroll
    for (int k = 0; k < 4; k++) {
        const int cur = k & 1, nxt = cur ^ 1;
        if (k < 3) {
#pragma unroll
            for (int i = 0; i < 4; i++) {
                float4 u = *(const float4*)(aa + (size_t)i * 16 * NODES + (k + 1) * 32);
                float4 v = *(const float4*)(aa + (size_t)i * 16 * NODES + (k + 1) * 32 + 4);
                pb[nxt][i] = cvt8(u, v);
            }
        }
        bf16x8 bb[4];
#pragma unroll
        for (int j = 0; j < 4; j++) {
            int R = wn * 64 + j * 16 + l15;
            int slot = (k * 4 + q) ^ (R & 15);
            bb[j] = *(const bf16x8*)(&Sb[R * 128 + slot * 8]);
        }
#pragma unroll
        for (int i = 0; i < 4; i++)
#pragma unroll
            for (int j = 0; j < 4; j++)
                acc2[i][j] = __builtin_amdgcn_mfma_f32_16x16x32_bf16(pb[cur][i], bb[j], acc2[i][j], 0, 0, 0);
    }

    // epilogue: + gcn_b -> mid[b][node][g]
    bf16_t* outb = mid + (size_t)b * NODES * NFEAT;
#pragma unroll
    for (int j = 0; j < 4; j++) {
        int g = n0 + wn * 64 + j * 16 + l15;
        float bias = gcn_b[g];
#pragma unroll
        for (int i = 0; i < 4; i++)
#pragma unroll
            for (int rr = 0; rr < 4; rr++) {
                int node = wm * 64 + i * 16 + q * 4 + rr;
                outb[(size_t)node * NFEAT + g] = (bf16_t)(acc2[i][j][rr] + bias);
            }
    }
#undef AS
}

// ---- stage 3 (bf16): BK=32 dbuf, LDK3=36 -> 36.9 KB LDS -> 4 blk/CU ----
// Chunked XCD swizzle: all 8 (m,n) blocks of one K-chunk on one XCD, adjacent
// -> A and B each fetched from HBM once chip-wide (~50 MB total).
template<int NITER>   // K per block = NITER*32
__global__ __launch_bounds__(256, 4)
void k_out_bf(const bf16_t* __restrict__ flat, const bf16_t* __restrict__ fcwb,
              bf16_t* __restrict__ part) {
    __shared__ __align__(16) bf16_t As[2][TILE * LDK3];
    __shared__ __align__(16) bf16_t Bs[2][TILE * LDK3];
    const int d = blockIdx.x;
    const int c = d & 7, s = d >> 3;
    const int xy = s & 7, zhi = s >> 3;
    const int z  = zhi * 8 + c;                 // K-chunk id
    const int m0 = (xy & 3) * TILE, n0 = (xy >> 2) * TILE;
    const int kb = z * (NITER * 32);
    const int tid = threadIdx.x;
    const int lane = tid & 63, w = tid >> 6, wm = w & 1, wn = w >> 1;
    const int l15 = lane & 15, q = lane >> 4;
    const int sr = tid >> 1, sc = tid & 1;      // staging: 2 threads/row, 32B each
    const bf16_t* fa = flat + (size_t)(m0 + sr) * KTOT + kb + sc * 16;
    const bf16_t* fb = fcwb + (size_t)(n0 + sr) * KTOT + kb + sc * 16;
    const int sadr = sr * LDK3 + sc * 16;

    struct L { bf16x8 lo, hi; };
    L ra[2], rb[2];
#define GLD(dst, p, t) { (dst).lo = *(const bf16x8*)((p) + (t) * 32); \
                         (dst).hi = *(const bf16x8*)((p) + (t) * 32 + 8); }
#define SST(base, v)   { *(bf16x8*)(base) = (v).lo; *(bf16x8*)((base) + 8) = (v).hi; }

    f32x4 acc[4][4] = {};
    GLD(ra[0], fa, 0); GLD(rb[0], fb, 0);
    GLD(ra[1], fa, 1); GLD(rb[1], fb, 1);
    SST(&As[0][sadr], ra[0]); SST(&Bs[0][sadr], rb[0]);
    bar();
#pragma unroll
    for (int t = 0; t < NITER; t++) {
        if (t + 2 < NITER) { GLD(ra[t & 1], fa, t + 2); GLD(rb[t & 1], fb, t + 2); }
        bf16x8 a[4], bq[4];
#pragma unroll
        for (int i = 0; i < 4; i++)
            a[i] = *(const bf16x8*)(&As[t & 1][(wm * 64 + i * 16 + l15) * LDK3 + q * 8]);
#pragma unroll
        for (int j = 0; j < 4; j++)
            bq[j] = *(const bf16x8*)(&Bs[t & 1][(wn * 64 + j * 16 + l15) * LDK3 + q * 8]);
#pragma unroll
        for (int i = 0; i < 4; i++)
#pragma unroll
            for (int j = 0; j < 4; j++)
                acc[i][j] = __builtin_amdgcn_mfma_f32_16x16x32_bf16(a[i], bq[j], acc[i][j], 0, 0, 0);
        if (t + 1 < NITER) {
            SST(&As[(t + 1) & 1][sadr], ra[(t + 1) & 1]);
            SST(&Bs[(t + 1) & 1][sadr], rb[(t + 1) & 1]);
        }
        bar();
    }
#undef GLD
#undef SST
    bf16_t* pb = part + (size_t)z * BATCH * NFEAT;
#pragma unroll
    for (int i = 0; i < 4; i++)
#pragma unroll
        for (int j = 0; j < 4; j++)
#pragma unroll
            for (int r = 0; r < 4; r++) {
                int bt_ = m0 + wm * 64 + i * 16 + q * 4 + r;
                int o   = n0 + wn * 64 + j * 16 + l15;
                pb[(size_t)bt_ * NFEAT + o] = (bf16_t)acc[i][j][r];
            }
}

// ---- stage 3 fp32-B fallback (only if ws too small for fcwb) ----
__global__ __launch_bounds__(256, 2)
void k_out_f32(const bf16_t* __restrict__ flat, const float* __restrict__ fcw,
               bf16_t* __restrict__ part) {
    __shared__ __align__(16) bf16_t As[2][TILE * LDK2];
    __shared__ __align__(16) bf16_t Bs[2][TILE * LDK2];
    const int m0 = blockIdx.x * TILE;
    const int n0 = blockIdx.y * TILE;
    const int kb = blockIdx.z * (KTOT / 64);
    const int tid = threadIdx.x;
    const int lane = tid & 63, w = tid >> 6, wm = w & 1, wn = w >> 1;
    const int l15 = lane & 15, q = lane >> 4;
    f32x4 acc[4][4] = {};
    const bf16_t* fa = flat + (size_t)m0 * KTOT;
    const float*  fb = fcw + (size_t)n0 * KTOT;

    AT2 ra[3]; XT2 rb[2];
    aload2(fa, KTOT, kb + 0 * BK2, tid, ra[0]);
    xload2(fb, KTOT, kb + 0 * BK2, tid, rb[0]);
    aload2(fa, KTOT, kb + 1 * BK2, tid, ra[1]);
    xload2(fb, KTOT, kb + 1 * BK2, tid, rb[1]);
    aload2(fa, KTOT, kb + 2 * BK2, tid, ra[2]);
    astore2(As[0], tid, ra[0]);
    xstore2(Bs[0], tid, rb[0]);
    bar();
#pragma unroll
    for (int k = 0; k < 8; k++) {
        if (k + 3 < 8) aload2(fa, KTOT, kb + (k + 3) * BK2, tid, ra[k % 3]);
        if (k + 2 < 8) xload2(fb, KTOT, kb + (k + 2) * BK2, tid, rb[k & 1]);
#pragma unroll
        for (int kk = 0; kk < BK2; kk += 32) {
            bf16x8 a[4], bbf[4];
#pragma unroll
            for (int i = 0; i < 4; i++)
                a[i] = *(const bf16x8*)(&As[k & 1][(wm * 64 + i * 16 + l15) * LDK2 + kk + q * 8]);
#pragma unroll
            for (int j = 0; j < 4; j++)
                bbf[j] = *(const bf16x8*)(&Bs[k & 1][(wn * 64 + j * 16 + l15) * LDK2 + kk + q * 8]);
#pragma unroll
            for (int i = 0; i < 4; i++)
#pragma unroll
                for (int j = 0; j < 4; j++)
                    acc[i][j] = __builtin_amdgcn_mfma_f32_16x16x32_bf16(a[i], bbf[j], acc[i][j], 0, 0, 0);
        }
        if (k + 1 < 8) {
            astore2(As[(k + 1) & 1], tid, ra[(k + 1) % 3]);
            xstore2(Bs[(k + 1) & 1], tid, rb[(k + 1) & 1]);
        }
        bar();
    }
    bf16_t* pb = part + (size_t)blockIdx.z * BATCH * NFEAT;
#pragma unroll
    for (int i = 0; i < 4; i++)
#pragma unroll
        for (int j = 0; j < 4; j++)
#pragma unroll
            for (int r = 0; r < 4; r++) {
                int bt_ = m0 + wm * 64 + i * 16 + q * 4 + r;
                int o   = n0 + wn * 64 + j * 16 + l15;
                pb[(size_t)bt_ * NFEAT + o] = (bf16_t)acc[i][j][r];
            }
}

// ---- stage 4: 2 threads per float4 output, shfl_xor(32) combine ----
// h==0 lanes write sum+fc_b to slots 0,2; h==1 lanes copy x[:,0,:] to slot 1.
template<int NSPL>
__global__ __launch_bounds__(256)
void k_reduce(const bf16_t* __restrict__ part, const float* __restrict__ fc_b,
              const float* __restrict__ x, float* __restrict__ out) {
    const int gt = blockIdx.x * 256 + threadIdx.x;      // 256 blocks
    const int wv = gt >> 6, l = gt & 63, h = l >> 5, li = l & 31;
    const int p = wv * 32 + li;                         // float4 index, 0..32767
    const int g4 = p * 4, o = g4 & (NFEAT - 1), b = g4 >> 8;
    float s0 = 0, s1 = 0, s2 = 0, s3 = 0;
    const bf16_t* pp = part + (size_t)(h * (NSPL / 2)) * BATCH * NFEAT + g4;
#pragma unroll 8
    for (int i = 0; i < NSPL / 2; i++) {
        bf16x4 v = *(const bf16x4*)(pp + (size_t)i * BATCH * NFEAT);
        s0 += (float)v[0]; s1 += (float)v[1]; s2 += (float)v[2]; s3 += (float)v[3];
    }
    s0 += __shfl_xor(s0, 32); s1 += __shfl_xor(s1, 32);
    s2 += __shfl_xor(s2, 32); s3 += __shfl_xor(s3, 32);
    if (h == 0) {
        const float4 cb = *(const float4*)(fc_b + o);
        float4 r = make_float4(s0 + cb.x, s1 + cb.y, s2 + cb.z, s3 + cb.w);
        *(float4*)(out + g4) = r;
        *(float4*)(out + 2 * BATCH * NFEAT + g4) = r;
    } else {
        *(float4*)(out + BATCH * NFEAT + g4) =
            *(const float4*)(x + (size_t)b * NODES * NFEAT + o);
    }
}

extern "C" void kernel_launch(void* const* d_in, const int* in_sizes, int n_in,
                              void* d_out, int out_size, void* d_ws, size_t ws_size,
                              hipStream_t stream) {
    const float* x     = (const float*)d_in[0];
    const float* adj   = (const float*)d_in[1];
    const float* gcn_w = (const float*)d_in[2];
    const float* gcn_b = (const float*)d_in[3];
    const float* fc_w  = (const float*)d_in[4];
    const float* fc_b  = (const float*)d_in[5];
    float* out = (float*)d_out;

    // ws: wT 128KB | mid 33.5M | part (spl x 512 x 256 bf16) | fcwb 16.8M
    const size_t midB   = (size_t)BATCH * NODES * NFEAT * 2;
    const size_t fcwB   = (size_t)NFEAT * KTOT * 2;
    const size_t p128B  = (size_t)128 * BATCH * NFEAT * 2;   // 33.5M
    const size_t p64B   = p128B / 2;

    int spl;
    if      (ws_size >= 131072 + midB + p128B + fcwB) spl = 128;
    else if (ws_size >= 131072 + midB + p64B  + fcwB) spl = 64;
    else                                              spl = 0;  // fp32 fallback

    bf16_t* wT   = (bf16_t*)d_ws;
    bf16_t* mid  = (bf16_t*)((char*)d_ws + 131072);
    bf16_t* part = (bf16_t*)((char*)d_ws + 131072 + midB);
    const size_t partB = (spl == 128) ? p128B : p64B;
    bf16_t* fcwb = (bf16_t*)((char*)d_ws + 131072 + midB + partB);

    const int nconv = spl ? 2048 : 0;
    k_prep   <<<dim3(nconv + 64), dim3(256), 0, stream>>>(gcn_w, wT, fc_w, fcwb, nconv);
    k_fused12<<<dim3(1024), dim3(256), 0, stream>>>(x, adj, wT, gcn_b, mid);
    if (spl == 128) {
        k_out_bf<8> <<<dim3(1024), dim3(256), 0, stream>>>(mid, fcwb, part);
        k_reduce<128><<<dim3(256), dim3(256), 0, stream>>>(part, fc_b, x, out);
    } else if (spl == 64) {
        k_out_bf<16><<<dim3(512), dim3(256), 0, stream>>>(mid, fcwb, part);
        k_reduce<64> <<<dim3(256), dim3(256), 0, stream>>>(part, fc_b, x, out);
    } else {
        k_out_f32<<<dim3(4, 2, 64), dim3(256), 0, stream>>>(mid, fc_w, part);
        k_reduce<64> <<<dim3(256), dim3(256), 0, stream>>>(part, fc_b, x, out);
    }
}

// Round 5
// 195.763 us; speedup vs baseline: 1.3165x; 1.3165x over previous
//
#include <hip/hip_runtime.h>

#define NODES 128
#define NFEAT 256
#define BATCH 512
#define KTOT  (NODES * NFEAT)   // 32768, stage-3 K
#define SPLIT 64                // stage-3 split-K factor
#define KCH   (KTOT / SPLIT)    // 512 per chunk

typedef __bf16 bf16_t;
typedef bf16_t bf16x4 __attribute__((ext_vector_type(4)));
typedef bf16_t bf16x8 __attribute__((ext_vector_type(8)));
typedef float  f32x4  __attribute__((ext_vector_type(4)));

#define BK    32
#define LDK   40     // bf16 LDS row stride, 32-wide tiles (80B)
#define BK2   64
#define LDK2  72     // bf16 LDS row stride, 64-wide tiles (144B)
#define TILE  128
#define FUSED_BLOCKS 1024
#define CONV_BLOCKS  2048   // fc_w fp32->bf16: 2048*256*16 = 8.39M floats

// Workgroup barrier WITHOUT the vmcnt(0) drain __syncthreads() emits.
// Only LDS (lgkmcnt) visibility is needed; global prefetch loads stay in flight.
__device__ __forceinline__ void bar() {
    asm volatile("s_waitcnt lgkmcnt(0)\n\ts_barrier" ::: "memory");
}

__device__ __forceinline__ bf16x8 cvt8(const float4 a, const float4 b) {
    bf16x8 t;
    t[0] = (bf16_t)a.x; t[1] = (bf16_t)a.y; t[2] = (bf16_t)a.z; t[3] = (bf16_t)a.w;
    t[4] = (bf16_t)b.x; t[5] = (bf16_t)b.y; t[6] = (bf16_t)b.z; t[7] = (bf16_t)b.w;
    return t;
}

// ---- fp32 128x32 tile: reg-load / LDS-store ----
struct XT { float4 v[4]; };
__device__ __forceinline__ void xload(const float* __restrict__ src, int ld, int k0,
                                      int tid, XT& t) {
#pragma unroll
    for (int i = 0; i < 2; i++) {
        int f = tid + i * 256, r = f >> 2, c = f & 3;
        t.v[2 * i]     = *(const float4*)(src + (size_t)r * ld + k0 + c * 8);
        t.v[2 * i + 1] = *(const float4*)(src + (size_t)r * ld + k0 + c * 8 + 4);
    }
}
__device__ __forceinline__ void xstore(bf16_t* __restrict__ dst, int tid, const XT& t) {
#pragma unroll
    for (int i = 0; i < 2; i++) {
        int f = tid + i * 256, r = f >> 2, c = f & 3;
        *(bf16x8*)(dst + r * LDK + c * 8) = cvt8(t.v[2 * i], t.v[2 * i + 1]);
    }
}

// ---- fp32 128x64 tile (k_out B, fp32 fallback path) ----
struct XT2 { float4 v[8]; };
__device__ __forceinline__ void xload2(const float* __restrict__ src, int ld, int k0,
                                       int tid, XT2& t) {
#pragma unroll
    for (int i = 0; i < 4; i++) {
        int f = tid + i * 256, r = f >> 3, c = f & 7;
        t.v[2 * i]     = *(const float4*)(src + (size_t)r * ld + k0 + c * 8);
        t.v[2 * i + 1] = *(const float4*)(src + (size_t)r * ld + k0 + c * 8 + 4);
    }
}
__device__ __forceinline__ void xstore2(bf16_t* __restrict__ dst, int tid, const XT2& t) {
#pragma unroll
    for (int i = 0; i < 4; i++) {
        int f = tid + i * 256, r = f >> 3, c = f & 7;
        *(bf16x8*)(dst + r * LDK2 + c * 8) = cvt8(t.v[2 * i], t.v[2 * i + 1]);
    }
}

// ---- bf16 128x64 tile (k_out A and bf16 B) ----
struct AT2 { bf16x8 v[4]; };
__device__ __forceinline__ void aload2(const bf16_t* __restrict__ src, int ld, int k0,
                                       int tid, AT2& t) {
#pragma unroll
    for (int i = 0; i < 4; i++) {
        int f = tid + i * 256, r = f >> 3, c = f & 7;
        t.v[i] = *(const bf16x8*)(src + (size_t)r * ld + k0 + c * 8);
    }
}
__device__ __forceinline__ void astore2(bf16_t* __restrict__ dst, int tid, const AT2& t) {
#pragma unroll
    for (int i = 0; i < 4; i++) {
        int f = tid + i * 256, r = f >> 3, c = f & 7;
        *(bf16x8*)(dst + r * LDK2 + c * 8) = t.v[i];
    }
}

// ---- pre-transpose gcn_w[k][g] -> wT[g][k] bf16 ----
__global__ __launch_bounds__(256)
void k_wt(const float* __restrict__ w, bf16_t* __restrict__ wT) {
    const int g0 = blockIdx.x * 4;
    const int k  = threadIdx.x;
    const float4 v = *(const float4*)(w + (size_t)k * NFEAT + g0);
    wT[(size_t)(g0 + 0) * NFEAT + k] = (bf16_t)v.x;
    wT[(size_t)(g0 + 1) * NFEAT + k] = (bf16_t)v.y;
    wT[(size_t)(g0 + 2) * NFEAT + k] = (bf16_t)v.z;
    wT[(size_t)(g0 + 3) * NFEAT + k] = (bf16_t)v.w;
}

// ---- fused stages 1+2: ROUND-0 structure (best measured: 56 us) ----
// Single-barrier dbuf, dist-3 reg pipeline, launch_bounds(256,3) -> VGPR 84
// (the (256,4) cap at 128 regs serialized loads in rounds 2-3 -> 96+ us).
// Riders vs round 0: (a) fc_w fp32->bf16 conversion appended as blocks
// 1024..3071 (R2 measured this ~free inside the dispatch; kills the ~14 us
// serial k_fwt and backfills CUs during the fused tail drain);
// (b) Sb stores packed as bf16x4 (same addresses, fewer LDS ops).
__global__ __launch_bounds__(256, 3)
void k_fused12(const float* __restrict__ x, const float* __restrict__ adj,
               const bf16_t* __restrict__ wT, const float* __restrict__ gcn_b,
               bf16_t* __restrict__ mid,
               const float* __restrict__ fcw, bf16_t* __restrict__ fcwb) {
    __shared__ __align__(16) bf16_t As[2][TILE * LDK];  // 2 x 10.2 KB
    __shared__ __align__(16) bf16_t Sb[TILE * TILE];    // 32 KB, XOR-swizzled

    if (blockIdx.x >= FUSED_BLOCKS) {                   // fc_w fp32 -> bf16
        const size_t base = ((size_t)(blockIdx.x - FUSED_BLOCKS) * 256 + threadIdx.x) * 16;
        const float4 a0 = *(const float4*)(fcw + base);
        const float4 a1 = *(const float4*)(fcw + base + 4);
        const float4 a2 = *(const float4*)(fcw + base + 8);
        const float4 a3 = *(const float4*)(fcw + base + 12);
        *(bf16x8*)(fcwb + base)     = cvt8(a0, a1);
        *(bf16x8*)(fcwb + base + 8) = cvt8(a2, a3);
        return;
    }

    // round-0 mapping: consecutive ids pair the two g-tiles of one batch;
    // L3 (die-level, 256 MB) dedups x/adj re-reads (R0: FETCH = ideal 99 MB).
    const int n0  = (blockIdx.x & 1) * TILE;            // g-tile (0 or 128)
    const int b   = blockIdx.x >> 1;
    const int tid = threadIdx.x;
    const int lane = tid & 63, w = tid >> 6, wm = w & 1, wn = w >> 1;
    const int l15 = lane & 15, q = lane >> 4;
    const float* xb   = x   + (size_t)b * NODES * NFEAT;
    const float* adjb = adj + (size_t)b * NODES * NODES;

    const bf16_t* wrow[4];
#pragma unroll
    for (int j = 0; j < 4; j++)
        wrow[j] = wT + (size_t)(n0 + wn * 64 + j * 16 + l15) * NFEAT + q * 8;

    // ---- stage 1: S = x[b] @ W  (K=256, 8 iters, 1 barrier/iter) ----
    f32x4 acc[4][4] = {};
    {
        XT r[3];
        xload(xb, NFEAT, 0 * BK, tid, r[0]);
        xload(xb, NFEAT, 1 * BK, tid, r[1]);
        xload(xb, NFEAT, 2 * BK, tid, r[2]);
        xstore(As[0], tid, r[0]);       // tile 0 -> buf 0
        bar();
#pragma unroll
        for (int k = 0; k < 8; k++) {
            if (k + 3 < 8) xload(xb, NFEAT, (k + 3) * BK, tid, r[k % 3]);  // dist-3
            bf16x8 bcur[4];
#pragma unroll
            for (int j = 0; j < 4; j++) bcur[j] = *(const bf16x8*)(wrow[j] + k * BK);
            bf16x8 a[4];
#pragma unroll
            for (int i = 0; i < 4; i++)
                a[i] = *(const bf16x8*)(&As[k & 1][(wm * 64 + i * 16 + l15) * LDK + q * 8]);
#pragma unroll
            for (int i = 0; i < 4; i++)
#pragma unroll
                for (int j = 0; j < 4; j++)
                    acc[i][j] = __builtin_amdgcn_mfma_f32_16x16x32_bf16(a[i], bcur[j], acc[i][j], 0, 0, 0);
            if (k + 1 < 8) xstore(As[(k + 1) & 1], tid, r[(k + 1) % 3]); // data 2 iters old
            bar();
        }
    }

    // preload adj tiles 0..2 while writing Sb
    XT r[3];
    xload(adjb, NODES, 0 * BK, tid, r[0]);
    xload(adjb, NODES, 1 * BK, tid, r[1]);
    xload(adjb, NODES, 2 * BK, tid, r[2]);
    // S -> Sb[g][m], XOR chunk swizzle: slot = (m>>3) ^ (g&15)
    // m>>3 and m&7 invariant across rr (q*4 base) -> bf16x4 packed store
#pragma unroll
    for (int i = 0; i < 4; i++)
#pragma unroll
        for (int j = 0; j < 4; j++) {
            int m = wm * 64 + i * 16 + q * 4;
            int g = wn * 64 + j * 16 + l15;
            int slot = (m >> 3) ^ (g & 15);
            bf16x4 v;
            v[0] = (bf16_t)acc[i][j][0]; v[1] = (bf16_t)acc[i][j][1];
            v[2] = (bf16_t)acc[i][j][2]; v[3] = (bf16_t)acc[i][j][3];
            *(bf16x4*)(&Sb[g * 128 + slot * 8 + (m & 7)]) = v;
        }
    bar();                              // Sb visible; stage-1 As reads done
    xstore(As[0], tid, r[0]);
    bar();

    // ---- stage 2: mid = adj[b] @ S  (K=128, 4 iters, 1 barrier/iter) ----
    f32x4 acc2[4][4] = {};
#pragma unroll
    for (int k = 0; k < 4; k++) {
        if (k + 3 < 4) xload(adjb, NODES, (k + 3) * BK, tid, r[k % 3]);
        bf16x8 a[4], bb[4];
#pragma unroll
        for (int i = 0; i < 4; i++)
            a[i] = *(const bf16x8*)(&As[k & 1][(wm * 64 + i * 16 + l15) * LDK + q * 8]);
#pragma unroll
        for (int j = 0; j < 4; j++) {
            int R = wn * 64 + j * 16 + l15;
            int slot = (k * 4 + q) ^ (R & 15);
            bb[j] = *(const bf16x8*)(&Sb[R * 128 + slot * 8]);
        }
#pragma unroll
        for (int i = 0; i < 4; i++)
#pragma unroll
            for (int j = 0; j < 4; j++)
                acc2[i][j] = __builtin_amdgcn_mfma_f32_16x16x32_bf16(a[i], bb[j], acc2[i][j], 0, 0, 0);
        if (k + 1 < 4) xstore(As[(k + 1) & 1], tid, r[(k + 1) % 3]);
        bar();
    }
    // epilogue: + gcn_b -> mid[b][node][g]  (R0-proven: WRITE_SIZE = ideal)
    bf16_t* outb = mid + (size_t)b * NODES * NFEAT;
#pragma unroll
    for (int j = 0; j < 4; j++) {
        int g = n0 + wn * 64 + j * 16 + l15;
        float bias = gcn_b[g];
#pragma unroll
        for (int i = 0; i < 4; i++)
#pragma unroll
            for (int rr = 0; rr < 4; rr++) {
                int node = wm * 64 + i * 16 + q * 4 + rr;
                outb[(size_t)node * NFEAT + g] = (bf16_t)(acc2[i][j][rr] + bias);
            }
    }
}

// ---- stage 3 (bf16 B): split-K=64, BK=64, single-barrier dbuf (R1/R2 best) ----
__global__ __launch_bounds__(256, 2)
void k_out_bf(const bf16_t* __restrict__ flat, const bf16_t* __restrict__ fcwb,
              bf16_t* __restrict__ part) {
    __shared__ __align__(16) bf16_t As[2][TILE * LDK2];  // 2 x 18.4 KB
    __shared__ __align__(16) bf16_t Bs[2][TILE * LDK2];  // 2 x 18.4 KB
    const int m0 = blockIdx.x * TILE;
    const int n0 = blockIdx.y * TILE;
    const int kb = blockIdx.z * KCH;     // 8 iters of BK2
    const int tid = threadIdx.x;
    const int lane = tid & 63, w = tid >> 6, wm = w & 1, wn = w >> 1;
    const int l15 = lane & 15, q = lane >> 4;
    f32x4 acc[4][4] = {};
    const bf16_t* fa = flat + (size_t)m0 * KTOT;
    const bf16_t* fb = fcwb + (size_t)n0 * KTOT;

    AT2 ra[3], rb[2];
    aload2(fa, KTOT, kb + 0 * BK2, tid, ra[0]);
    aload2(fb, KTOT, kb + 0 * BK2, tid, rb[0]);
    aload2(fa, KTOT, kb + 1 * BK2, tid, ra[1]);
    aload2(fb, KTOT, kb + 1 * BK2, tid, rb[1]);
    aload2(fa, KTOT, kb + 2 * BK2, tid, ra[2]);
    astore2(As[0], tid, ra[0]);
    astore2(Bs[0], tid, rb[0]);
    bar();
#pragma unroll
    for (int k = 0; k < 8; k++) {
        if (k + 3 < 8) aload2(fa, KTOT, kb + (k + 3) * BK2, tid, ra[k % 3]);   // A dist-3
        if (k + 2 < 8) aload2(fb, KTOT, kb + (k + 2) * BK2, tid, rb[k & 1]);   // B dist-2
#pragma unroll
        for (int kk = 0; kk < BK2; kk += 32) {
            bf16x8 a[4], bbf[4];
#pragma unroll
            for (int i = 0; i < 4; i++)
                a[i] = *(const bf16x8*)(&As[k & 1][(wm * 64 + i * 16 + l15) * LDK2 + kk + q * 8]);
#pragma unroll
            for (int j = 0; j < 4; j++)
                bbf[j] = *(const bf16x8*)(&Bs[k & 1][(wn * 64 + j * 16 + l15) * LDK2 + kk + q * 8]);
#pragma unroll
            for (int i = 0; i < 4; i++)
#pragma unroll
                for (int j = 0; j < 4; j++)
                    acc[i][j] = __builtin_amdgcn_mfma_f32_16x16x32_bf16(a[i], bbf[j], acc[i][j], 0, 0, 0);
        }
        if (k + 1 < 8) {
            astore2(As[(k + 1) & 1], tid, ra[(k + 1) % 3]);
            astore2(Bs[(k + 1) & 1], tid, rb[(k + 1) & 1]);
        }
        bar();
    }
    bf16_t* pb = part + (size_t)blockIdx.z * BATCH * NFEAT;
#pragma unroll
    for (int i = 0; i < 4; i++)
#pragma unroll
        for (int j = 0; j < 4; j++)
#pragma unroll
            for (int r = 0; r < 4; r++) {
                int bt_ = m0 + wm * 64 + i * 16 + q * 4 + r;
                int o   = n0 + wn * 64 + j * 16 + l15;
                pb[(size_t)bt_ * NFEAT + o] = (bf16_t)acc[i][j][r];
            }
}

// ---- stage 3 (fp32 B fallback, used only if ws too small for fcwb) ----
__global__ __launch_bounds__(256, 2)
void k_out(const bf16_t* __restrict__ flat, const float* __restrict__ fcw,
           bf16_t* __restrict__ part) {
    __shared__ __align__(16) bf16_t As[2][TILE * LDK2];
    __shared__ __align__(16) bf16_t Bs[2][TILE * LDK2];
    const int m0 = blockIdx.x * TILE;
    const int n0 = blockIdx.y * TILE;
    const int kb = blockIdx.z * KCH;
    const int tid = threadIdx.x;
    const int lane = tid & 63, w = tid >> 6, wm = w & 1, wn = w >> 1;
    const int l15 = lane & 15, q = lane >> 4;
    f32x4 acc[4][4] = {};
    const bf16_t* fa = flat + (size_t)m0 * KTOT;
    const float*  fb = fcw + (size_t)n0 * KTOT;

    AT2 ra[3]; XT2 rb[2];
    aload2(fa, KTOT, kb + 0 * BK2, tid, ra[0]);
    xload2(fb, KTOT, kb + 0 * BK2, tid, rb[0]);
    aload2(fa, KTOT, kb + 1 * BK2, tid, ra[1]);
    xload2(fb, KTOT, kb + 1 * BK2, tid, rb[1]);
    aload2(fa, KTOT, kb + 2 * BK2, tid, ra[2]);
    astore2(As[0], tid, ra[0]);
    xstore2(Bs[0], tid, rb[0]);
    bar();
#pragma unroll
    for (int k = 0; k < 8; k++) {
        if (k + 3 < 8) aload2(fa, KTOT, kb + (k + 3) * BK2, tid, ra[k % 3]);
        if (k + 2 < 8) xload2(fb, KTOT, kb + (k + 2) * BK2, tid, rb[k & 1]);
#pragma unroll
        for (int kk = 0; kk < BK2; kk += 32) {
            bf16x8 a[4], bbf[4];
#pragma unroll
            for (int i = 0; i < 4; i++)
                a[i] = *(const bf16x8*)(&As[k & 1][(wm * 64 + i * 16 + l15) * LDK2 + kk + q * 8]);
#pragma unroll
            for (int j = 0; j < 4; j++)
                bbf[j] = *(const bf16x8*)(&Bs[k & 1][(wn * 64 + j * 16 + l15) * LDK2 + kk + q * 8]);
#pragma unroll
            for (int i = 0; i < 4; i++)
#pragma unroll
                for (int j = 0; j < 4; j++)
                    acc[i][j] = __builtin_amdgcn_mfma_f32_16x16x32_bf16(a[i], bbf[j], acc[i][j], 0, 0, 0);
        }
        if (k + 1 < 8) {
            astore2(As[(k + 1) & 1], tid, ra[(k + 1) % 3]);
            xstore2(Bs[(k + 1) & 1], tid, rb[(k + 1) & 1]);
        }
        bar();
    }
    bf16_t* pb = part + (size_t)blockIdx.z * BATCH * NFEAT;
#pragma unroll
    for (int i = 0; i < 4; i++)
#pragma unroll
        for (int j = 0; j < 4; j++)
#pragma unroll
            for (int r = 0; r < 4; r++) {
                int bt_ = m0 + wm * 64 + i * 16 + q * 4 + r;
                int o   = n0 + wn * 64 + j * 16 + l15;
                pb[(size_t)bt_ * NFEAT + o] = (bf16_t)acc[i][j][r];
            }
}

// ---- stage 4: reduce bf16 partials + fc_b -> slots 0,2; x[:,0,:] -> slot 1 ----
__global__ __launch_bounds__(256)
void k_reduce(const bf16_t* __restrict__ part, const float* __restrict__ fc_b,
              const float* __restrict__ x, float* __restrict__ out) {
    const int g4 = (blockIdx.x * 256 + threadIdx.x) * 4;   // 128 blocks
    const int o = g4 & (NFEAT - 1), b = g4 >> 8;
    float s[4];
    const float4 c0 = *(const float4*)(fc_b + o);
    s[0] = c0.x; s[1] = c0.y; s[2] = c0.z; s[3] = c0.w;
#pragma unroll 8
    for (int i = 0; i < SPLIT; i++) {
        bf16x4 p = *(const bf16x4*)(part + (size_t)i * BATCH * NFEAT + g4);
#pragma unroll
        for (int j = 0; j < 4; j++) s[j] += (float)p[j];
    }
    float4 o0 = make_float4(s[0], s[1], s[2], s[3]);
    *(float4*)(out + g4) = o0;
    *(float4*)(out + 2 * BATCH * NFEAT + g4) = o0;
    *(float4*)(out + BATCH * NFEAT + g4) = *(const float4*)(x + (size_t)b * NODES * NFEAT + o);
}

extern "C" void kernel_launch(void* const* d_in, const int* in_sizes, int n_in,
                              void* d_out, int out_size, void* d_ws, size_t ws_size,
                              hipStream_t stream) {
    const float* x     = (const float*)d_in[0];
    const float* adj   = (const float*)d_in[1];
    const float* gcn_w = (const float*)d_in[2];
    const float* gcn_b = (const float*)d_in[3];
    const float* fc_w  = (const float*)d_in[4];
    const float* fc_b  = (const float*)d_in[5];
    float* out = (float*)d_out;

    // ws: wT 128KB | mid 33.5MB | part (bf16) 16.8MB | fcwb (bf16) 16.8MB => ~67.2 MB
    const size_t midB  = (size_t)BATCH * NODES * NFEAT * 2;
    const size_t partB = (size_t)SPLIT * BATCH * NFEAT * 2;
    const size_t fcwB  = (size_t)NFEAT * KTOT * 2;
    bf16_t* wT   = (bf16_t*)d_ws;
    bf16_t* mid  = (bf16_t*)((char*)d_ws + 131072);
    bf16_t* part = (bf16_t*)((char*)d_ws + 131072 + midB);
    bf16_t* fcwb = (bf16_t*)((char*)d_ws + 131072 + midB + partB);
    const bool cv = ws_size >= 131072 + midB + partB + fcwB;

    k_wt     <<<dim3(64), dim3(256), 0, stream>>>(gcn_w, wT);
    k_fused12<<<dim3(cv ? FUSED_BLOCKS + CONV_BLOCKS : FUSED_BLOCKS), dim3(256), 0, stream>>>(
        x, adj, wT, gcn_b, mid, fc_w, fcwb);
    if (cv)
        k_out_bf<<<dim3(4, 2, SPLIT), dim3(256), 0, stream>>>(mid, fcwb, part);
    else
        k_out   <<<dim3(4, 2, SPLIT), dim3(256), 0, stream>>>(mid, fc_w, part);
    k_reduce <<<dim3(128), dim3(256), 0, stream>>>(part, fc_b, x, out);
}